// Round 1
// baseline (901.530 us; speedup 1.0000x reference)
//
#include <hip/hip_runtime.h>
#include <hip/hip_bf16.h>
#include <cstdint>

typedef __bf16 bf16_t;
typedef bf16_t bf16x8 __attribute__((ext_vector_type(8)));
typedef float f32x4 __attribute__((ext_vector_type(4)));

#define DEVI __device__ __forceinline__

DEVI void gload_lds16(const void* g, void* l) {
    __builtin_amdgcn_global_load_lds((const __attribute__((address_space(1))) void*)g,
                                     (__attribute__((address_space(3))) void*)l, 16, 0, 0);
}

// ---------------- transpose + f32->bf16 pack: dst[n][k] = src[k][n] ----------------
__global__ __launch_bounds__(256) void transpose_f32_bf16(
    const float* __restrict__ src, bf16_t* __restrict__ dst,
    int ldsrc, int lddst, long srcBatchStride, long dstBatchStride)
{
    __shared__ float tile[32][33];
    src += (long)blockIdx.z * srcBatchStride;
    dst += (long)blockIdx.z * dstBatchStride;
    const int bx = blockIdx.x * 32;   // src col
    const int by = blockIdx.y * 32;   // src row
    const int tx = threadIdx.x, ty = threadIdx.y;
    #pragma unroll
    for (int j = 0; j < 32; j += 8)
        tile[ty + j][tx] = src[(size_t)(by + ty + j) * ldsrc + bx + tx];
    __syncthreads();
    #pragma unroll
    for (int j = 0; j < 32; j += 8)
        dst[(size_t)(bx + ty + j) * lddst + by + tx] = (bf16_t)tile[tx][ty + j];
}

// ---------------- LayerNorm (ddof=1 per reference), f32 in -> bf16 out ----------------
__global__ __launch_bounds__(256) void ln_kernel(
    const float* __restrict__ x, const float* __restrict__ g,
    const float* __restrict__ b, bf16_t* __restrict__ out)
{
    const int row = blockIdx.x;
    const int tid = threadIdx.x;
    __shared__ float red[8];
    const float4 v = ((const float4*)(x + (size_t)row * 1024))[tid];
    float s = v.x + v.y + v.z + v.w;
    #pragma unroll
    for (int m = 32; m; m >>= 1) s += __shfl_xor(s, m);
    if ((tid & 63) == 0) red[tid >> 6] = s;
    __syncthreads();
    const float mean = (red[0] + red[1] + red[2] + red[3]) * (1.f / 1024.f);
    const float dx = v.x - mean, dy = v.y - mean, dz = v.z - mean, dw = v.w - mean;
    float ss = dx * dx + dy * dy + dz * dz + dw * dw;
    #pragma unroll
    for (int m = 32; m; m >>= 1) ss += __shfl_xor(ss, m);
    if ((tid & 63) == 0) red[4 + (tid >> 6)] = ss;
    __syncthreads();
    const float var = (red[4] + red[5] + red[6] + red[7]) * (1.f / 1023.f);
    const float rstd = rsqrtf(var + 1e-5f);
    const float4 gv = ((const float4*)g)[tid];
    const float4 bv = ((const float4*)b)[tid];
    union { bf16_t h[4]; uint2 u; } pk;
    pk.h[0] = (bf16_t)(dx * rstd * gv.x + bv.x);
    pk.h[1] = (bf16_t)(dy * rstd * gv.y + bv.y);
    pk.h[2] = (bf16_t)(dz * rstd * gv.z + bv.z);
    pk.h[3] = (bf16_t)(dw * rstd * gv.w + bv.w);
    *((uint2*)(out + (size_t)row * 1024 + tid * 4)) = pk.u;
}

// ---------------- GEMM: C[M,N] = A[M,K] @ BT[N,K]^T, bf16 MFMA, f32 acc ----------------
// EPI 0: bf16 out (no bias).  EPI 1: f32 out = acc + bias + res.  EPI 2: bf16 out = relu(acc + bias).
template <int EPI>
__global__ __launch_bounds__(256) void gemm_bt(
    const bf16_t* __restrict__ A, const bf16_t* __restrict__ BT,
    void* __restrict__ Cout, const float* __restrict__ bias,
    const float* __restrict__ res, int M, int N, int K)
{
    constexpr int BK = 64;
    __shared__ bf16_t As[128 * BK];
    __shared__ bf16_t Bs[128 * BK];
    const int tid = threadIdx.x;
    const int lane = tid & 63;
    const int wid = tid >> 6;
    const int m0 = blockIdx.y * 128, n0 = blockIdx.x * 128;
    const int lrow = lane & 15, lgrp = lane >> 4;
    const int mw = (wid >> 1) * 64, nw = (wid & 1) * 64;
    f32x4 acc[4][4] = {};

    for (int k0 = 0; k0 < K; k0 += BK) {
        __syncthreads();
        #pragma unroll
        for (int i = 0; i < 4; ++i) {
            const int c = i * 256 + tid;
            const int row = c >> 3, kc = (c & 7) * 8;
            gload_lds16(A + (size_t)(m0 + row) * K + k0 + kc, &As[c * 8]);
        }
        #pragma unroll
        for (int i = 0; i < 4; ++i) {
            const int c = i * 256 + tid;
            const int row = c >> 3, kc = (c & 7) * 8;
            gload_lds16(BT + (size_t)(n0 + row) * K + k0 + kc, &Bs[c * 8]);
        }
        __syncthreads();
        #pragma unroll
        for (int kk = 0; kk < BK; kk += 32) {
            bf16x8 af[4], bfr[4];
            #pragma unroll
            for (int mi = 0; mi < 4; ++mi)
                af[mi] = *(const bf16x8*)&As[(mw + mi * 16 + lrow) * BK + kk + lgrp * 8];
            #pragma unroll
            for (int ni = 0; ni < 4; ++ni)
                bfr[ni] = *(const bf16x8*)&Bs[(nw + ni * 16 + lrow) * BK + kk + lgrp * 8];
            #pragma unroll
            for (int mi = 0; mi < 4; ++mi)
                #pragma unroll
                for (int ni = 0; ni < 4; ++ni)
                    acc[mi][ni] = __builtin_amdgcn_mfma_f32_16x16x32_bf16(
                        af[mi], bfr[ni], acc[mi][ni], 0, 0, 0);
        }
    }

    #pragma unroll
    for (int mi = 0; mi < 4; ++mi) {
        #pragma unroll
        for (int r = 0; r < 4; ++r) {
            const int row = m0 + mw + mi * 16 + lgrp * 4 + r;
            #pragma unroll
            for (int ni = 0; ni < 4; ++ni) {
                const int col = n0 + nw + ni * 16 + lrow;
                const float v = acc[mi][ni][r];
                if (EPI == 0) {
                    ((bf16_t*)Cout)[(size_t)row * N + col] = (bf16_t)v;
                } else if (EPI == 1) {
                    ((float*)Cout)[(size_t)row * N + col] =
                        v + bias[col] + res[(size_t)row * N + col];
                } else {
                    const float t = v + bias[col];
                    ((bf16_t*)Cout)[(size_t)row * N + col] = (bf16_t)(t > 0.f ? t : 0.f);
                }
            }
        }
    }
}

// ---------------- causal flash attention; scores scaled by +sqrt(hs)=8 (faithful) ----------------
// qkv: [B*T, 3072] bf16 (Q|K|V, each col h*64+d).  O: [B*T, 1024] bf16 (concat heads).
__global__ __launch_bounds__(256) void attn_kernel(
    const bf16_t* __restrict__ qkv, bf16_t* __restrict__ O)
{
    const int tid = threadIdx.x, lane = tid & 63, wid = tid >> 6;
    const int lrow = lane & 15, lgrp = lane >> 4;
    const int qb = blockIdx.x * 64;
    const int b = blockIdx.y >> 4, h = blockIdx.y & 15;
    const bf16_t* base = qkv + (size_t)b * 2048 * 3072;

    __shared__ bf16_t Ks[32 * 64];       // [key][d]
    __shared__ bf16_t Vt[64 * 32];       // [d][key]
    __shared__ bf16_t Pl[4][16 * 32];    // per-wave [q][key]

    const int qrow = qb + wid * 16;
    const bf16_t* qptr = base + (size_t)(qrow + lrow) * 3072 + h * 64 + lgrp * 8;
    const bf16x8 qf0 = *(const bf16x8*)qptr;
    const bf16x8 qf1 = *(const bf16x8*)(qptr + 32);

    float m_r[4], l_r[4];
    f32x4 of[4] = {};
    #pragma unroll
    for (int r = 0; r < 4; ++r) { m_r[r] = -INFINITY; l_r[r] = 0.f; }

    const int skey = tid >> 3, skc = (tid & 7) * 8;
    for (int kv = 0; kv < qb + 64; kv += 32) {
        __syncthreads();
        // stage K tile [32][64] via async global->LDS
        gload_lds16(base + (size_t)(kv + skey) * 3072 + 1024 + h * 64 + skc, &Ks[tid * 8]);
        // stage V transposed [64][32] via regs
        {
            const bf16x8 vv = *(const bf16x8*)(base + (size_t)(kv + skey) * 3072 + 2048 + h * 64 + skc);
            #pragma unroll
            for (int j = 0; j < 8; ++j) Vt[(skc + j) * 32 + skey] = vv[j];
        }
        __syncthreads();

        if (kv <= qrow + 15) {
            f32x4 s0 = {}, s1 = {};
            const bf16x8 k00 = *(const bf16x8*)&Ks[lrow * 64 + lgrp * 8];
            const bf16x8 k01 = *(const bf16x8*)&Ks[lrow * 64 + 32 + lgrp * 8];
            const bf16x8 k10 = *(const bf16x8*)&Ks[(16 + lrow) * 64 + lgrp * 8];
            const bf16x8 k11 = *(const bf16x8*)&Ks[(16 + lrow) * 64 + 32 + lgrp * 8];
            s0 = __builtin_amdgcn_mfma_f32_16x16x32_bf16(qf0, k00, s0, 0, 0, 0);
            s0 = __builtin_amdgcn_mfma_f32_16x16x32_bf16(qf1, k01, s0, 0, 0, 0);
            s1 = __builtin_amdgcn_mfma_f32_16x16x32_bf16(qf0, k10, s1, 0, 0, 0);
            s1 = __builtin_amdgcn_mfma_f32_16x16x32_bf16(qf1, k11, s1, 0, 0, 0);

            const int key0 = kv + lrow, key1 = kv + 16 + lrow;
            float alpha[4], p0[4], p1[4];
            #pragma unroll
            for (int r = 0; r < 4; ++r) {
                const int q = qrow + lgrp * 4 + r;
                float a = (key0 <= q) ? s0[r] * 8.f : -INFINITY;
                float c = (key1 <= q) ? s1[r] * 8.f : -INFINITY;
                float mx = fmaxf(a, c);
                #pragma unroll
                for (int mm = 8; mm; mm >>= 1) mx = fmaxf(mx, __shfl_xor(mx, mm));
                const float mnew = fmaxf(m_r[r], mx);
                alpha[r] = (m_r[r] == -INFINITY) ? 0.f : __expf(m_r[r] - mnew);
                p0[r] = __expf(a - mnew);
                p1[r] = __expf(c - mnew);
                float rs = p0[r] + p1[r];
                #pragma unroll
                for (int mm = 8; mm; mm >>= 1) rs += __shfl_xor(rs, mm);
                l_r[r] = l_r[r] * alpha[r] + rs;
                m_r[r] = mnew;
            }
            #pragma unroll
            for (int dg = 0; dg < 4; ++dg)
                #pragma unroll
                for (int r = 0; r < 4; ++r) of[dg][r] *= alpha[r];

            // P -> LDS [q][key] for the PV A-operand transpose
            #pragma unroll
            for (int r = 0; r < 4; ++r) {
                Pl[wid][(lgrp * 4 + r) * 32 + lrow]      = (bf16_t)p0[r];
                Pl[wid][(lgrp * 4 + r) * 32 + 16 + lrow] = (bf16_t)p1[r];
            }
            asm volatile("s_waitcnt lgkmcnt(0)" ::: "memory");
            const bf16x8 pf = *(const bf16x8*)&Pl[wid][lrow * 32 + lgrp * 8];
            #pragma unroll
            for (int dg = 0; dg < 4; ++dg) {
                const bf16x8 vf = *(const bf16x8*)&Vt[(dg * 16 + lrow) * 32 + lgrp * 8];
                of[dg] = __builtin_amdgcn_mfma_f32_16x16x32_bf16(pf, vf, of[dg], 0, 0, 0);
            }
        }
    }

    #pragma unroll
    for (int dg = 0; dg < 4; ++dg)
        #pragma unroll
        for (int r = 0; r < 4; ++r) {
            const size_t row = (size_t)b * 2048 + qrow + lgrp * 4 + r;
            O[row * 1024 + h * 64 + dg * 16 + lrow] = (bf16_t)(of[dg][r] / l_r[r]);
        }
}

// ---------------- host ----------------
extern "C" void kernel_launch(void* const* d_in, const int* in_sizes, int n_in,
                              void* d_out, int out_size, void* d_ws, size_t ws_size,
                              hipStream_t stream)
{
    const float* x   = (const float*)d_in[0];
    const float* Wq  = (const float*)d_in[1];
    const float* Wk  = (const float*)d_in[2];
    const float* Wv  = (const float*)d_in[3];
    const float* Wp  = (const float*)d_in[4];
    const float* bp  = (const float*)d_in[5];
    const float* W1  = (const float*)d_in[6];
    const float* b1  = (const float*)d_in[7];
    const float* W2  = (const float*)d_in[8];
    const float* b2  = (const float*)d_in[9];
    const float* g1  = (const float*)d_in[10];
    const float* be1 = (const float*)d_in[11];
    const float* g2  = (const float*)d_in[12];
    const float* be2 = (const float*)d_in[13];

    char* w = (char*)d_ws;
    auto alloc = [&](size_t bytes) { char* p = w; w += (bytes + 255) & ~255ull; return p; };
    bf16_t* wqkvT = (bf16_t*)alloc((size_t)3072 * 1024 * 2);
    bf16_t* wpT   = (bf16_t*)alloc((size_t)1024 * 1024 * 2);
    bf16_t* w1T   = (bf16_t*)alloc((size_t)4096 * 1024 * 2);
    bf16_t* w2T   = (bf16_t*)alloc((size_t)1024 * 4096 * 2);
    bf16_t* h     = (bf16_t*)alloc((size_t)8192 * 1024 * 2);
    bf16_t* qkv   = (bf16_t*)alloc((size_t)8192 * 3072 * 2);
    float*  x2    = (float*)alloc((size_t)8192 * 1024 * 4);
    bf16_t* act   = (bf16_t*)alloc((size_t)8192 * 4096 * 2);
    bf16_t* o     = h;    // h dead after QKV GEMM
    bf16_t* h2    = qkv;  // qkv dead after attention

    const dim3 tblk(32, 8);
    // pack weights (transposed, bf16)
    transpose_f32_bf16<<<dim3(2, 32, 16), tblk, 0, stream>>>(Wq, wqkvT,                64, 1024, 1024 * 64, 64 * 1024);
    transpose_f32_bf16<<<dim3(2, 32, 16), tblk, 0, stream>>>(Wk, wqkvT + 1024 * 1024,  64, 1024, 1024 * 64, 64 * 1024);
    transpose_f32_bf16<<<dim3(2, 32, 16), tblk, 0, stream>>>(Wv, wqkvT + 2048 * 1024,  64, 1024, 1024 * 64, 64 * 1024);
    transpose_f32_bf16<<<dim3(32, 32, 1),  tblk, 0, stream>>>(Wp, wpT, 1024, 1024, 0, 0);
    transpose_f32_bf16<<<dim3(128, 32, 1), tblk, 0, stream>>>(W1, w1T, 4096, 1024, 0, 0);
    transpose_f32_bf16<<<dim3(32, 128, 1), tblk, 0, stream>>>(W2, w2T, 1024, 4096, 0, 0);

    // LN1
    ln_kernel<<<8192, 256, 0, stream>>>(x, g1, be1, h);
    // QKV projection
    gemm_bt<0><<<dim3(24, 64), 256, 0, stream>>>(h, wqkvT, qkv, nullptr, nullptr, 8192, 3072, 1024);
    // causal attention
    attn_kernel<<<dim3(32, 64), 256, 0, stream>>>(qkv, o);
    // output proj + bias + residual -> x2 (f32)
    gemm_bt<1><<<dim3(8, 64), 256, 0, stream>>>(o, wpT, x2, bp, x, 8192, 1024, 1024);
    // LN2
    ln_kernel<<<8192, 256, 0, stream>>>(x2, g2, be2, h2);
    // FFN up + ReLU
    gemm_bt<2><<<dim3(32, 64), 256, 0, stream>>>(h2, w1T, act, b1, nullptr, 8192, 4096, 1024);
    // FFN down + bias + residual -> out (f32)
    gemm_bt<1><<<dim3(8, 64), 256, 0, stream>>>(act, w2T, d_out, b2, x2, 8192, 1024, 4096);
}

// Round 3
// 769.449 us; speedup vs baseline: 1.1717x; 1.1717x over previous
//
#include <hip/hip_runtime.h>
#include <hip/hip_bf16.h>
#include <cstdint>

typedef __bf16 bf16_t;
typedef bf16_t bf16x8 __attribute__((ext_vector_type(8)));
typedef float f32x4 __attribute__((ext_vector_type(4)));

#define DEVI __device__ __forceinline__

DEVI void gload_lds16(const void* g, void* l) {
    __builtin_amdgcn_global_load_lds((const __attribute__((address_space(1))) void*)g,
                                     (__attribute__((address_space(3))) void*)l, 16, 0, 0);
}

// ---------------- transpose + f32->bf16 pack: dst[n][k] = src[k][n] ----------------
__global__ __launch_bounds__(256) void transpose_f32_bf16(
    const float* __restrict__ src, bf16_t* __restrict__ dst,
    int ldsrc, int lddst, long srcBatchStride, long dstBatchStride)
{
    __shared__ float tile[32][33];
    src += (long)blockIdx.z * srcBatchStride;
    dst += (long)blockIdx.z * dstBatchStride;
    const int bx = blockIdx.x * 32;   // src col
    const int by = blockIdx.y * 32;   // src row
    const int tx = threadIdx.x, ty = threadIdx.y;
    #pragma unroll
    for (int j = 0; j < 32; j += 8)
        tile[ty + j][tx] = src[(size_t)(by + ty + j) * ldsrc + bx + tx];
    __syncthreads();
    #pragma unroll
    for (int j = 0; j < 32; j += 8)
        dst[(size_t)(bx + ty + j) * lddst + by + tx] = (bf16_t)tile[tx][ty + j];
}

// ---------------- LayerNorm (ddof=1 per reference), f32 in -> bf16 out ----------------
__global__ __launch_bounds__(256) void ln_kernel(
    const float* __restrict__ x, const float* __restrict__ g,
    const float* __restrict__ b, bf16_t* __restrict__ out)
{
    const int row = blockIdx.x;
    const int tid = threadIdx.x;
    __shared__ float red[8];
    const float4 v = ((const float4*)(x + (size_t)row * 1024))[tid];
    float s = v.x + v.y + v.z + v.w;
    #pragma unroll
    for (int m = 32; m; m >>= 1) s += __shfl_xor(s, m);
    if ((tid & 63) == 0) red[tid >> 6] = s;
    __syncthreads();
    const float mean = (red[0] + red[1] + red[2] + red[3]) * (1.f / 1024.f);
    const float dx = v.x - mean, dy = v.y - mean, dz = v.z - mean, dw = v.w - mean;
    float ss = dx * dx + dy * dy + dz * dz + dw * dw;
    #pragma unroll
    for (int m = 32; m; m >>= 1) ss += __shfl_xor(ss, m);
    if ((tid & 63) == 0) red[4 + (tid >> 6)] = ss;
    __syncthreads();
    const float var = (red[4] + red[5] + red[6] + red[7]) * (1.f / 1023.f);
    const float rstd = rsqrtf(var + 1e-5f);
    const float4 gv = ((const float4*)g)[tid];
    const float4 bv = ((const float4*)b)[tid];
    union { bf16_t h[4]; uint2 u; } pk;
    pk.h[0] = (bf16_t)(dx * rstd * gv.x + bv.x);
    pk.h[1] = (bf16_t)(dy * rstd * gv.y + bv.y);
    pk.h[2] = (bf16_t)(dz * rstd * gv.z + bv.z);
    pk.h[3] = (bf16_t)(dw * rstd * gv.w + bv.w);
    *((uint2*)(out + (size_t)row * 1024 + tid * 4)) = pk.u;
}

// ---------------- GEMM: C[M,N] = A[M,K] @ BT[N,K]^T, bf16 MFMA, f32 acc ----------------
// EPI 0: bf16 out (no bias).  EPI 1: f32 out = acc + bias + res.  EPI 2: bf16 out = relu(acc + bias).
template <int EPI>
__global__ __launch_bounds__(256) void gemm_bt(
    const bf16_t* __restrict__ A, const bf16_t* __restrict__ BT,
    void* __restrict__ Cout, const float* __restrict__ bias,
    const float* __restrict__ res, int M, int N, int K)
{
    constexpr int BK = 64;
    __shared__ bf16_t As[128 * BK];
    __shared__ bf16_t Bs[128 * BK];
    const int tid = threadIdx.x;
    const int lane = tid & 63;
    const int wid = tid >> 6;
    const int m0 = blockIdx.y * 128, n0 = blockIdx.x * 128;
    const int lrow = lane & 15, lgrp = lane >> 4;
    const int mw = (wid >> 1) * 64, nw = (wid & 1) * 64;
    f32x4 acc[4][4] = {};

    for (int k0 = 0; k0 < K; k0 += BK) {
        __syncthreads();
        #pragma unroll
        for (int i = 0; i < 4; ++i) {
            const int c = i * 256 + tid;
            const int row = c >> 3, kc = (c & 7) * 8;
            gload_lds16(A + (size_t)(m0 + row) * K + k0 + kc, &As[c * 8]);
        }
        #pragma unroll
        for (int i = 0; i < 4; ++i) {
            const int c = i * 256 + tid;
            const int row = c >> 3, kc = (c & 7) * 8;
            gload_lds16(BT + (size_t)(n0 + row) * K + k0 + kc, &Bs[c * 8]);
        }
        __syncthreads();
        #pragma unroll
        for (int kk = 0; kk < BK; kk += 32) {
            bf16x8 af[4], bfr[4];
            #pragma unroll
            for (int mi = 0; mi < 4; ++mi)
                af[mi] = *(const bf16x8*)&As[(mw + mi * 16 + lrow) * BK + kk + lgrp * 8];
            #pragma unroll
            for (int ni = 0; ni < 4; ++ni)
                bfr[ni] = *(const bf16x8*)&Bs[(nw + ni * 16 + lrow) * BK + kk + lgrp * 8];
            #pragma unroll
            for (int mi = 0; mi < 4; ++mi)
                #pragma unroll
                for (int ni = 0; ni < 4; ++ni)
                    acc[mi][ni] = __builtin_amdgcn_mfma_f32_16x16x32_bf16(
                        af[mi], bfr[ni], acc[mi][ni], 0, 0, 0);
        }
    }

    #pragma unroll
    for (int mi = 0; mi < 4; ++mi) {
        #pragma unroll
        for (int r = 0; r < 4; ++r) {
            const int row = m0 + mw + mi * 16 + lgrp * 4 + r;
            #pragma unroll
            for (int ni = 0; ni < 4; ++ni) {
                const int col = n0 + nw + ni * 16 + lrow;
                const float v = acc[mi][ni][r];
                if (EPI == 0) {
                    ((bf16_t*)Cout)[(size_t)row * N + col] = (bf16_t)v;
                } else if (EPI == 1) {
                    ((float*)Cout)[(size_t)row * N + col] =
                        v + bias[col] + res[(size_t)row * N + col];
                } else {
                    const float t = v + bias[col];
                    ((bf16_t*)Cout)[(size_t)row * N + col] = (bf16_t)(t > 0.f ? t : 0.f);
                }
            }
        }
    }
}

// ---------------- causal flash attention v2 ----------------
// QBLK=128 (4 waves x 32 q-rows), KVBLK=64.  K fragments direct from global.
// V staged transposed in LDS with XOR col-block swizzle; P via per-wave swizzled LDS.
// Q pre-scaled by 8 (faithful scores * sqrt(hs)).
__global__ __launch_bounds__(256) void attn_kernel(
    const bf16_t* __restrict__ qkv, bf16_t* __restrict__ O)
{
    const int tid = threadIdx.x, lane = tid & 63, wid = tid >> 6;
    const int lrow = lane & 15, lgrp = lane >> 4;
    const int qb = (15 - blockIdx.x) * 128;            // heavy blocks first
    const int b = blockIdx.y >> 4, h = blockIdx.y & 15;
    const bf16_t* base  = qkv + (size_t)b * 2048 * 3072;
    const bf16_t* Kbase = base + 1024 + h * 64;
    const bf16_t* Vbase = base + 2048 + h * 64;

    __shared__ bf16_t Vt[64 * 64];       // swizzled transposed V: (key,d) at d*64 + ((key>>3 ^ (d&7))<<3) + (key&7)
    __shared__ bf16_t Pl[4][32 * 64];    // per-wave swizzled P: (q,key) at q*64 + ((key>>3 ^ (q&7))<<3) + (key&7)

    const int mw = wid * 32;

    // Q fragments, pre-scaled by 8
    bf16x8 qf[2][2];
    #pragma unroll
    for (int mi = 0; mi < 2; ++mi)
        #pragma unroll
        for (int dh = 0; dh < 2; ++dh) {
            bf16x8 t = *(const bf16x8*)(base + (size_t)(qb + mw + mi * 16 + lrow) * 3072
                                        + h * 64 + dh * 32 + lgrp * 8);
            #pragma unroll
            for (int j = 0; j < 8; ++j) t[j] = (bf16_t)((float)t[j] * 8.0f);
            qf[mi][dh] = t;
        }

    f32x4 of[2][4] = {};
    float m_r[2][4], l_r[2][4];
    #pragma unroll
    for (int mi = 0; mi < 2; ++mi)
        #pragma unroll
        for (int r = 0; r < 4; ++r) { m_r[mi][r] = -INFINITY; l_r[mi][r] = 0.f; }

    const int kvlen = qb + 128;
    for (int kv = 0; kv < kvlen; kv += 64) {
        __syncthreads();
        // ---- stage V transposed+swizzled: one wave covers all 64 keys ----
        #pragma unroll
        for (int i = 0; i < 2; ++i) {
            const int key = tid & 63;
            const int dc8 = (tid >> 6) + i * 4;      // 0..7 : d-chunk of 8
            const bf16x8 vv = *(const bf16x8*)(Vbase + (size_t)(kv + key) * 3072 + dc8 * 8);
            #pragma unroll
            for (int j = 0; j < 8; ++j)
                Vt[(dc8 * 8 + j) * 64 + (((key >> 3) ^ j) << 3) + (key & 7)] = vv[j];
        }
        __syncthreads();

        const bool act0 = (kv <= qb + mw + 15);
        const bool act1 = (kv <= qb + mw + 31);
        if (act1) {
            // ---- K fragments direct from global (L2-resident) ----
            bf16x8 kf[4][2];
            #pragma unroll
            for (int kt = 0; kt < 4; ++kt)
                #pragma unroll
                for (int dh = 0; dh < 2; ++dh)
                    kf[kt][dh] = *(const bf16x8*)(Kbase + (size_t)(kv + kt * 16 + lrow) * 3072
                                                  + dh * 32 + lgrp * 8);

            #pragma unroll
            for (int mi = 0; mi < 2; ++mi) {
                if (mi == 0 && !act0) continue;
                // ---- S = Q K^T (x8 folded into Q) ----
                f32x4 s[4] = {};
                #pragma unroll
                for (int kt = 0; kt < 4; ++kt) {
                    s[kt] = __builtin_amdgcn_mfma_f32_16x16x32_bf16(qf[mi][0], kf[kt][0], s[kt], 0, 0, 0);
                    s[kt] = __builtin_amdgcn_mfma_f32_16x16x32_bf16(qf[mi][1], kf[kt][1], s[kt], 0, 0, 0);
                }
                // ---- online softmax (rows r) ----
                float p[4][4];
                #pragma unroll
                for (int r = 0; r < 4; ++r) {
                    const int q = qb + mw + mi * 16 + lgrp * 4 + r;
                    float v0 = (kv + 0 * 16 + lrow <= q) ? s[0][r] : -INFINITY;
                    float v1 = (kv + 1 * 16 + lrow <= q) ? s[1][r] : -INFINITY;
                    float v2 = (kv + 2 * 16 + lrow <= q) ? s[2][r] : -INFINITY;
                    float v3 = (kv + 3 * 16 + lrow <= q) ? s[3][r] : -INFINITY;
                    float mx = fmaxf(fmaxf(v0, v1), fmaxf(v2, v3));
                    #pragma unroll
                    for (int mm = 8; mm; mm >>= 1) mx = fmaxf(mx, __shfl_xor(mx, mm));
                    const float mnew = fmaxf(m_r[mi][r], mx);
                    const float alpha = __expf(m_r[mi][r] - mnew);
                    p[0][r] = __expf(v0 - mnew);
                    p[1][r] = __expf(v1 - mnew);
                    p[2][r] = __expf(v2 - mnew);
                    p[3][r] = __expf(v3 - mnew);
                    float rs = p[0][r] + p[1][r] + p[2][r] + p[3][r];
                    #pragma unroll
                    for (int mm = 8; mm; mm >>= 1) rs += __shfl_xor(rs, mm);
                    l_r[mi][r] = l_r[mi][r] * alpha + rs;
                    m_r[mi][r] = mnew;
                    #pragma unroll
                    for (int dg = 0; dg < 4; ++dg) of[mi][dg][r] *= alpha;
                }
                // ---- P -> per-wave swizzled LDS ----
                #pragma unroll
                for (int kt = 0; kt < 4; ++kt)
                    #pragma unroll
                    for (int r = 0; r < 4; ++r) {
                        const int qi = mi * 16 + lgrp * 4 + r;
                        const int ki = kt * 16 + lrow;
                        Pl[wid][qi * 64 + ((((ki >> 3) ^ (qi & 7))) << 3) + (ki & 7)] = (bf16_t)p[kt][r];
                    }
            }
            asm volatile("s_waitcnt lgkmcnt(0)" ::: "memory");
            __builtin_amdgcn_sched_barrier(0);

            // ---- PV ----
            bf16x8 vf[4][2];
            #pragma unroll
            for (int dg = 0; dg < 4; ++dg) {
                const int d = dg * 16 + lrow;
                #pragma unroll
                for (int kh = 0; kh < 2; ++kh)
                    vf[dg][kh] = *(const bf16x8*)&Vt[d * 64 + ((((kh * 4 + lgrp) ^ (d & 7))) << 3)];
            }
            #pragma unroll
            for (int mi = 0; mi < 2; ++mi) {
                if (mi == 0 && !act0) continue;
                const int qrow = mi * 16 + lrow;
                #pragma unroll
                for (int kh = 0; kh < 2; ++kh) {
                    const bf16x8 pf = *(const bf16x8*)&Pl[wid][qrow * 64 + ((((kh * 4 + lgrp) ^ (lrow & 7))) << 3)];
                    #pragma unroll
                    for (int dg = 0; dg < 4; ++dg)
                        of[mi][dg] = __builtin_amdgcn_mfma_f32_16x16x32_bf16(pf, vf[dg][kh], of[mi][dg], 0, 0, 0);
                }
            }
        }
    }

    // ---- epilogue ----
    #pragma unroll
    for (int mi = 0; mi < 2; ++mi)
        #pragma unroll
        for (int dg = 0; dg < 4; ++dg)
            #pragma unroll
            for (int r = 0; r < 4; ++r) {
                const size_t row = (size_t)b * 2048 + qb + mw + mi * 16 + lgrp * 4 + r;
                O[row * 1024 + h * 64 + dg * 16 + lrow] = (bf16_t)(of[mi][dg][r] / l_r[mi][r]);
            }
}

// ---------------- host ----------------
extern "C" void kernel_launch(void* const* d_in, const int* in_sizes, int n_in,
                              void* d_out, int out_size, void* d_ws, size_t ws_size,
                              hipStream_t stream)
{
    const float* x   = (const float*)d_in[0];
    const float* Wq  = (const float*)d_in[1];
    const float* Wk  = (const float*)d_in[2];
    const float* Wv  = (const float*)d_in[3];
    const float* Wp  = (const float*)d_in[4];
    const float* bp  = (const float*)d_in[5];
    const float* W1  = (const float*)d_in[6];
    const float* b1  = (const float*)d_in[7];
    const float* W2  = (const float*)d_in[8];
    const float* b2  = (const float*)d_in[9];
    const float* g1  = (const float*)d_in[10];
    const float* be1 = (const float*)d_in[11];
    const float* g2  = (const float*)d_in[12];
    const float* be2 = (const float*)d_in[13];

    char* w = (char*)d_ws;
    auto alloc = [&](size_t bytes) { char* p = w; w += (bytes + 255) & ~255ull; return p; };
    bf16_t* wqkvT = (bf16_t*)alloc((size_t)3072 * 1024 * 2);
    bf16_t* wpT   = (bf16_t*)alloc((size_t)1024 * 1024 * 2);
    bf16_t* w1T   = (bf16_t*)alloc((size_t)4096 * 1024 * 2);
    bf16_t* w2T   = (bf16_t*)alloc((size_t)1024 * 4096 * 2);
    bf16_t* h     = (bf16_t*)alloc((size_t)8192 * 1024 * 2);
    bf16_t* qkv   = (bf16_t*)alloc((size_t)8192 * 3072 * 2);
    float*  x2    = (float*)alloc((size_t)8192 * 1024 * 4);
    bf16_t* act   = (bf16_t*)alloc((size_t)8192 * 4096 * 2);
    bf16_t* o     = h;    // h dead after QKV GEMM
    bf16_t* h2    = qkv;  // qkv dead after attention

    const dim3 tblk(32, 8);
    // pack weights (transposed, bf16)
    transpose_f32_bf16<<<dim3(2, 32, 16), tblk, 0, stream>>>(Wq, wqkvT,                64, 1024, 1024 * 64, 64 * 1024);
    transpose_f32_bf16<<<dim3(2, 32, 16), tblk, 0, stream>>>(Wk, wqkvT + 1024 * 1024,  64, 1024, 1024 * 64, 64 * 1024);
    transpose_f32_bf16<<<dim3(2, 32, 16), tblk, 0, stream>>>(Wv, wqkvT + 2048 * 1024,  64, 1024, 1024 * 64, 64 * 1024);
    transpose_f32_bf16<<<dim3(32, 32, 1),  tblk, 0, stream>>>(Wp, wpT, 1024, 1024, 0, 0);
    transpose_f32_bf16<<<dim3(128, 32, 1), tblk, 0, stream>>>(W1, w1T, 4096, 1024, 0, 0);
    transpose_f32_bf16<<<dim3(32, 128, 1), tblk, 0, stream>>>(W2, w2T, 1024, 4096, 0, 0);

    // LN1
    ln_kernel<<<8192, 256, 0, stream>>>(x, g1, be1, h);
    // QKV projection
    gemm_bt<0><<<dim3(24, 64), 256, 0, stream>>>(h, wqkvT, qkv, nullptr, nullptr, 8192, 3072, 1024);
    // causal attention
    attn_kernel<<<dim3(16, 64), 256, 0, stream>>>(qkv, o);
    // output proj + bias + residual -> x2 (f32)
    gemm_bt<1><<<dim3(8, 64), 256, 0, stream>>>(o, wpT, x2, bp, x, 8192, 1024, 1024);
    // LN2
    ln_kernel<<<8192, 256, 0, stream>>>(x2, g2, be2, h2);
    // FFN up + ReLU
    gemm_bt<2><<<dim3(32, 64), 256, 0, stream>>>(h2, w1T, act, b1, nullptr, 8192, 4096, 1024);
    // FFN down + bias + residual -> out (f32)
    gemm_bt<1><<<dim3(8, 64), 256, 0, stream>>>(act, w2T, d_out, b2, x2, 8192, 1024, 4096);
}

// Round 4
// 698.657 us; speedup vs baseline: 1.2904x; 1.1013x over previous
//
#include <hip/hip_runtime.h>
#include <hip/hip_bf16.h>
#include <cstdint>

typedef __bf16 bf16_t;
typedef bf16_t bf16x8 __attribute__((ext_vector_type(8)));
typedef float f32x4 __attribute__((ext_vector_type(4)));

#define DEVI __device__ __forceinline__

DEVI void gload_lds16(const void* g, void* l) {
    __builtin_amdgcn_global_load_lds((const __attribute__((address_space(1))) void*)g,
                                     (__attribute__((address_space(3))) void*)l, 16, 0, 0);
}

// ---------------- transpose + f32->bf16 pack: dst[n][k] = src[k][n] ----------------
__global__ __launch_bounds__(256) void transpose_f32_bf16(
    const float* __restrict__ src, bf16_t* __restrict__ dst,
    int ldsrc, int lddst, long srcBatchStride, long dstBatchStride)
{
    __shared__ float tile[32][33];
    src += (long)blockIdx.z * srcBatchStride;
    dst += (long)blockIdx.z * dstBatchStride;
    const int bx = blockIdx.x * 32;   // src col
    const int by = blockIdx.y * 32;   // src row
    const int tx = threadIdx.x, ty = threadIdx.y;
    #pragma unroll
    for (int j = 0; j < 32; j += 8)
        tile[ty + j][tx] = src[(size_t)(by + ty + j) * ldsrc + bx + tx];
    __syncthreads();
    #pragma unroll
    for (int j = 0; j < 32; j += 8)
        dst[(size_t)(bx + ty + j) * lddst + by + tx] = (bf16_t)tile[tx][ty + j];
}

// ---------------- LayerNorm (ddof=1 per reference), f32 in -> bf16 out ----------------
__global__ __launch_bounds__(256) void ln_kernel(
    const float* __restrict__ x, const float* __restrict__ g,
    const float* __restrict__ b, bf16_t* __restrict__ out)
{
    const int row = blockIdx.x;
    const int tid = threadIdx.x;
    __shared__ float red[8];
    const float4 v = ((const float4*)(x + (size_t)row * 1024))[tid];
    float s = v.x + v.y + v.z + v.w;
    #pragma unroll
    for (int m = 32; m; m >>= 1) s += __shfl_xor(s, m);
    if ((tid & 63) == 0) red[tid >> 6] = s;
    __syncthreads();
    const float mean = (red[0] + red[1] + red[2] + red[3]) * (1.f / 1024.f);
    const float dx = v.x - mean, dy = v.y - mean, dz = v.z - mean, dw = v.w - mean;
    float ss = dx * dx + dy * dy + dz * dz + dw * dw;
    #pragma unroll
    for (int m = 32; m; m >>= 1) ss += __shfl_xor(ss, m);
    if ((tid & 63) == 0) red[4 + (tid >> 6)] = ss;
    __syncthreads();
    const float var = (red[4] + red[5] + red[6] + red[7]) * (1.f / 1023.f);
    const float rstd = rsqrtf(var + 1e-5f);
    const float4 gv = ((const float4*)g)[tid];
    const float4 bv = ((const float4*)b)[tid];
    union { bf16_t h[4]; uint2 u; } pk;
    pk.h[0] = (bf16_t)(dx * rstd * gv.x + bv.x);
    pk.h[1] = (bf16_t)(dy * rstd * gv.y + bv.y);
    pk.h[2] = (bf16_t)(dz * rstd * gv.z + bv.z);
    pk.h[3] = (bf16_t)(dw * rstd * gv.w + bv.w);
    *((uint2*)(out + (size_t)row * 1024 + tid * 4)) = pk.u;
}

// ---------------- GEMM: C[M,N] = A[M,K] @ BT[N,K]^T, bf16 MFMA, f32 acc ----------------
// EPI 0: bf16 out (no bias).  EPI 1: f32 out = acc + bias + res.  EPI 2: bf16 out = relu(acc + bias).
template <int EPI>
__global__ __launch_bounds__(256) void gemm_bt(
    const bf16_t* __restrict__ A, const bf16_t* __restrict__ BT,
    void* __restrict__ Cout, const float* __restrict__ bias,
    const float* __restrict__ res, int M, int N, int K)
{
    constexpr int BK = 64;
    __shared__ bf16_t As[128 * BK];
    __shared__ bf16_t Bs[128 * BK];
    const int tid = threadIdx.x;
    const int lane = tid & 63;
    const int wid = tid >> 6;
    const int m0 = blockIdx.y * 128, n0 = blockIdx.x * 128;
    const int lrow = lane & 15, lgrp = lane >> 4;
    const int mw = (wid >> 1) * 64, nw = (wid & 1) * 64;
    f32x4 acc[4][4] = {};

    for (int k0 = 0; k0 < K; k0 += BK) {
        __syncthreads();
        #pragma unroll
        for (int i = 0; i < 4; ++i) {
            const int c = i * 256 + tid;
            const int row = c >> 3, kc = (c & 7) * 8;
            gload_lds16(A + (size_t)(m0 + row) * K + k0 + kc, &As[c * 8]);
        }
        #pragma unroll
        for (int i = 0; i < 4; ++i) {
            const int c = i * 256 + tid;
            const int row = c >> 3, kc = (c & 7) * 8;
            gload_lds16(BT + (size_t)(n0 + row) * K + k0 + kc, &Bs[c * 8]);
        }
        __syncthreads();
        #pragma unroll
        for (int kk = 0; kk < BK; kk += 32) {
            bf16x8 af[4], bfr[4];
            #pragma unroll
            for (int mi = 0; mi < 4; ++mi)
                af[mi] = *(const bf16x8*)&As[(mw + mi * 16 + lrow) * BK + kk + lgrp * 8];
            #pragma unroll
            for (int ni = 0; ni < 4; ++ni)
                bfr[ni] = *(const bf16x8*)&Bs[(nw + ni * 16 + lrow) * BK + kk + lgrp * 8];
            #pragma unroll
            for (int mi = 0; mi < 4; ++mi)
                #pragma unroll
                for (int ni = 0; ni < 4; ++ni)
                    acc[mi][ni] = __builtin_amdgcn_mfma_f32_16x16x32_bf16(
                        af[mi], bfr[ni], acc[mi][ni], 0, 0, 0);
        }
    }

    #pragma unroll
    for (int mi = 0; mi < 4; ++mi) {
        #pragma unroll
        for (int r = 0; r < 4; ++r) {
            const int row = m0 + mw + mi * 16 + lgrp * 4 + r;
            #pragma unroll
            for (int ni = 0; ni < 4; ++ni) {
                const int col = n0 + nw + ni * 16 + lrow;
                const float v = acc[mi][ni][r];
                if (EPI == 0) {
                    ((bf16_t*)Cout)[(size_t)row * N + col] = (bf16_t)v;
                } else if (EPI == 1) {
                    ((float*)Cout)[(size_t)row * N + col] =
                        v + bias[col] + res[(size_t)row * N + col];
                } else {
                    const float t = v + bias[col];
                    ((bf16_t*)Cout)[(size_t)row * N + col] = (bf16_t)(t > 0.f ? t : 0.f);
                }
            }
        }
    }
}

// ---------------- causal flash attention v3 ----------------
// Balanced: grid (8, B*H); block x runs q-tile (15-x) then q-tile x  -> 34 KV-tile units each.
// Pipelined: next tile's V-regs + K-frags issued after barrier B, drained at next barrier A.
// QBLK=128 (4 waves x 32 rows), KVBLK=64; swizzled Vt/Pl (conflict-free); Q pre-scaled by 8.
__global__ __launch_bounds__(256) void attn_kernel(
    const bf16_t* __restrict__ qkv, bf16_t* __restrict__ O)
{
    const int tid = threadIdx.x, lane = tid & 63, wid = tid >> 6;
    const int lrow = lane & 15, lgrp = lane >> 4;
    const int b = blockIdx.y >> 4, h = blockIdx.y & 15;
    const bf16_t* base  = qkv + (size_t)b * 2048 * 3072;
    const bf16_t* Kbase = base + 1024 + h * 64;
    const bf16_t* Vbase = base + 2048 + h * 64;

    __shared__ bf16_t Vt[64 * 64];       // swizzled: (key,d) at d*64 + ((key>>3 ^ (d&7))<<3) + (key&7)
    __shared__ bf16_t Pl[4][32 * 64];    // per-wave swizzled: (q,key) at q*64 + ((key>>3 ^ (q&7))<<3) + (key&7)

    const int mw = wid * 32;
    const int vkey = tid & 63;           // V-staging: key this thread loads
    const int vdc  = tid >> 6;           // V-staging: d-chunk base (8 d's per chunk)

    for (int pass = 0; pass < 2; ++pass) {
        const int jq = (pass == 0) ? 15 - (int)blockIdx.x : (int)blockIdx.x;
        const int qb = jq * 128;
        const int nt = (qb + 128) >> 6;

        // Q fragments, pre-scaled by 8 (faithful scores * sqrt(hs))
        bf16x8 qf[2][2];
        #pragma unroll
        for (int mi = 0; mi < 2; ++mi)
            #pragma unroll
            for (int dh = 0; dh < 2; ++dh) {
                bf16x8 t = *(const bf16x8*)(base + (size_t)(qb + mw + mi * 16 + lrow) * 3072
                                            + h * 64 + dh * 32 + lgrp * 8);
                #pragma unroll
                for (int j = 0; j < 8; ++j) t[j] = (bf16_t)((float)t[j] * 8.0f);
                qf[mi][dh] = t;
            }

        f32x4 of[2][4] = {};
        float m_r[2][4], l_r[2][4];
        #pragma unroll
        for (int mi = 0; mi < 2; ++mi)
            #pragma unroll
            for (int r = 0; r < 4; ++r) { m_r[mi][r] = -INFINITY; l_r[mi][r] = 0.f; }

        // prologue: prefetch tile 0
        bf16x8 vvc[2], kfc[4][2];
        #pragma unroll
        for (int i = 0; i < 2; ++i)
            vvc[i] = *(const bf16x8*)(Vbase + (size_t)vkey * 3072 + (vdc + i * 4) * 8);
        #pragma unroll
        for (int kt = 0; kt < 4; ++kt)
            #pragma unroll
            for (int dh = 0; dh < 2; ++dh)
                kfc[kt][dh] = *(const bf16x8*)(Kbase + (size_t)(kt * 16 + lrow) * 3072
                                               + dh * 32 + lgrp * 8);

        for (int t = 0; t < nt; ++t) {
            const int kv = t << 6;
            __syncthreads();   // A: prev PV done with Vt; drains our in-flight prefetch (needed for vvc)
            // ---- write V tile (transposed + swizzled) from regs ----
            #pragma unroll
            for (int i = 0; i < 2; ++i) {
                const int dc8 = vdc + i * 4;
                #pragma unroll
                for (int j = 0; j < 8; ++j)
                    Vt[(dc8 * 8 + j) * 64 + (((vkey >> 3) ^ j) << 3) + (vkey & 7)] = vvc[i][j];
            }
            __syncthreads();   // B: Vt visible

            // ---- issue next tile's loads; they fly through the whole compute phase ----
            bf16x8 vvn[2], kfn[4][2];
            const bool hasn = (t + 1 < nt);
            if (hasn) {
                const int kv2 = kv + 64;
                #pragma unroll
                for (int i = 0; i < 2; ++i)
                    vvn[i] = *(const bf16x8*)(Vbase + (size_t)(kv2 + vkey) * 3072 + (vdc + i * 4) * 8);
                #pragma unroll
                for (int kt = 0; kt < 4; ++kt)
                    #pragma unroll
                    for (int dh = 0; dh < 2; ++dh)
                        kfn[kt][dh] = *(const bf16x8*)(Kbase + (size_t)(kv2 + kt * 16 + lrow) * 3072
                                                       + dh * 32 + lgrp * 8);
            }

            const bool act0 = (kv <= qb + mw + 15);
            const bool act1 = (kv <= qb + mw + 31);
            if (act1) {
                #pragma unroll
                for (int mi = 0; mi < 2; ++mi) {
                    if (mi == 0 && !act0) continue;
                    // ---- S = Q K^T ----
                    f32x4 s[4] = {};
                    __builtin_amdgcn_s_setprio(1);
                    #pragma unroll
                    for (int kt = 0; kt < 4; ++kt) {
                        s[kt] = __builtin_amdgcn_mfma_f32_16x16x32_bf16(qf[mi][0], kfc[kt][0], s[kt], 0, 0, 0);
                        s[kt] = __builtin_amdgcn_mfma_f32_16x16x32_bf16(qf[mi][1], kfc[kt][1], s[kt], 0, 0, 0);
                    }
                    __builtin_amdgcn_s_setprio(0);
                    // ---- online softmax: shuffle-reduce max only; l kept lane-partial ----
                    float p[4][4];
                    #pragma unroll
                    for (int r = 0; r < 4; ++r) {
                        const int q = qb + mw + mi * 16 + lgrp * 4 + r;
                        float v0 = (kv + 0 * 16 + lrow <= q) ? s[0][r] : -INFINITY;
                        float v1 = (kv + 1 * 16 + lrow <= q) ? s[1][r] : -INFINITY;
                        float v2 = (kv + 2 * 16 + lrow <= q) ? s[2][r] : -INFINITY;
                        float v3 = (kv + 3 * 16 + lrow <= q) ? s[3][r] : -INFINITY;
                        float mx = fmaxf(fmaxf(v0, v1), fmaxf(v2, v3));
                        #pragma unroll
                        for (int mm = 8; mm; mm >>= 1) mx = fmaxf(mx, __shfl_xor(mx, mm));
                        const float mnew = fmaxf(m_r[mi][r], mx);
                        const float alpha = __expf(m_r[mi][r] - mnew);
                        p[0][r] = __expf(v0 - mnew);
                        p[1][r] = __expf(v1 - mnew);
                        p[2][r] = __expf(v2 - mnew);
                        p[3][r] = __expf(v3 - mnew);
                        l_r[mi][r] = l_r[mi][r] * alpha + (p[0][r] + p[1][r] + p[2][r] + p[3][r]);
                        m_r[mi][r] = mnew;
                        #pragma unroll
                        for (int dg = 0; dg < 4; ++dg) of[mi][dg][r] *= alpha;
                    }
                    // ---- P -> per-wave swizzled LDS ----
                    #pragma unroll
                    for (int kt = 0; kt < 4; ++kt)
                        #pragma unroll
                        for (int r = 0; r < 4; ++r) {
                            const int qi = mi * 16 + lgrp * 4 + r;
                            const int ki = kt * 16 + lrow;
                            Pl[wid][qi * 64 + ((((ki >> 3) ^ (qi & 7))) << 3) + (ki & 7)] = (bf16_t)p[kt][r];
                        }
                }
                asm volatile("s_waitcnt lgkmcnt(0)" ::: "memory");
                __builtin_amdgcn_sched_barrier(0);

                // ---- PV ----
                bf16x8 vf[4][2];
                #pragma unroll
                for (int dg = 0; dg < 4; ++dg) {
                    const int d = dg * 16 + lrow;
                    #pragma unroll
                    for (int kh = 0; kh < 2; ++kh)
                        vf[dg][kh] = *(const bf16x8*)&Vt[d * 64 + ((((kh * 4 + lgrp) ^ (d & 7))) << 3)];
                }
                __builtin_amdgcn_s_setprio(1);
                #pragma unroll
                for (int mi = 0; mi < 2; ++mi) {
                    if (mi == 0 && !act0) continue;
                    const int qrow = mi * 16 + lrow;
                    #pragma unroll
                    for (int kh = 0; kh < 2; ++kh) {
                        const bf16x8 pf = *(const bf16x8*)&Pl[wid][qrow * 64 + ((((kh * 4 + lgrp) ^ (lrow & 7))) << 3)];
                        #pragma unroll
                        for (int dg = 0; dg < 4; ++dg)
                            of[mi][dg] = __builtin_amdgcn_mfma_f32_16x16x32_bf16(pf, vf[dg][kh], of[mi][dg], 0, 0, 0);
                    }
                }
                __builtin_amdgcn_s_setprio(0);
            }

            if (hasn) {
                #pragma unroll
                for (int i = 0; i < 2; ++i) vvc[i] = vvn[i];
                #pragma unroll
                for (int kt = 0; kt < 4; ++kt)
                    #pragma unroll
                    for (int dh = 0; dh < 2; ++dh) kfc[kt][dh] = kfn[kt][dh];
            }
        }

        // ---- epilogue: reduce lane-partial l across the 16-lane row group, write O ----
        #pragma unroll
        for (int mi = 0; mi < 2; ++mi)
            #pragma unroll
            for (int r = 0; r < 4; ++r) {
                float l = l_r[mi][r];
                #pragma unroll
                for (int mm = 8; mm; mm >>= 1) l += __shfl_xor(l, mm);
                l_r[mi][r] = l;
            }
        #pragma unroll
        for (int mi = 0; mi < 2; ++mi)
            #pragma unroll
            for (int dg = 0; dg < 4; ++dg)
                #pragma unroll
                for (int r = 0; r < 4; ++r) {
                    const size_t row = (size_t)b * 2048 + qb + mw + mi * 16 + lgrp * 4 + r;
                    O[row * 1024 + h * 64 + dg * 16 + lrow] = (bf16_t)(of[mi][dg][r] / l_r[mi][r]);
                }
    }
}

// ---------------- host ----------------
extern "C" void kernel_launch(void* const* d_in, const int* in_sizes, int n_in,
                              void* d_out, int out_size, void* d_ws, size_t ws_size,
                              hipStream_t stream)
{
    const float* x   = (const float*)d_in[0];
    const float* Wq  = (const float*)d_in[1];
    const float* Wk  = (const float*)d_in[2];
    const float* Wv  = (const float*)d_in[3];
    const float* Wp  = (const float*)d_in[4];
    const float* bp  = (const float*)d_in[5];
    const float* W1  = (const float*)d_in[6];
    const float* b1  = (const float*)d_in[7];
    const float* W2  = (const float*)d_in[8];
    const float* b2  = (const float*)d_in[9];
    const float* g1  = (const float*)d_in[10];
    const float* be1 = (const float*)d_in[11];
    const float* g2  = (const float*)d_in[12];
    const float* be2 = (const float*)d_in[13];

    char* w = (char*)d_ws;
    auto alloc = [&](size_t bytes) { char* p = w; w += (bytes + 255) & ~255ull; return p; };
    bf16_t* wqkvT = (bf16_t*)alloc((size_t)3072 * 1024 * 2);
    bf16_t* wpT   = (bf16_t*)alloc((size_t)1024 * 1024 * 2);
    bf16_t* w1T   = (bf16_t*)alloc((size_t)4096 * 1024 * 2);
    bf16_t* w2T   = (bf16_t*)alloc((size_t)1024 * 4096 * 2);
    bf16_t* h     = (bf16_t*)alloc((size_t)8192 * 1024 * 2);
    bf16_t* qkv   = (bf16_t*)alloc((size_t)8192 * 3072 * 2);
    float*  x2    = (float*)alloc((size_t)8192 * 1024 * 4);
    bf16_t* act   = (bf16_t*)alloc((size_t)8192 * 4096 * 2);
    bf16_t* o     = h;    // h dead after QKV GEMM
    bf16_t* h2    = qkv;  // qkv dead after attention

    const dim3 tblk(32, 8);
    // pack weights (transposed, bf16)
    transpose_f32_bf16<<<dim3(2, 32, 16), tblk, 0, stream>>>(Wq, wqkvT,                64, 1024, 1024 * 64, 64 * 1024);
    transpose_f32_bf16<<<dim3(2, 32, 16), tblk, 0, stream>>>(Wk, wqkvT + 1024 * 1024,  64, 1024, 1024 * 64, 64 * 1024);
    transpose_f32_bf16<<<dim3(2, 32, 16), tblk, 0, stream>>>(Wv, wqkvT + 2048 * 1024,  64, 1024, 1024 * 64, 64 * 1024);
    transpose_f32_bf16<<<dim3(32, 32, 1),  tblk, 0, stream>>>(Wp, wpT, 1024, 1024, 0, 0);
    transpose_f32_bf16<<<dim3(128, 32, 1), tblk, 0, stream>>>(W1, w1T, 4096, 1024, 0, 0);
    transpose_f32_bf16<<<dim3(32, 128, 1), tblk, 0, stream>>>(W2, w2T, 1024, 4096, 0, 0);

    // LN1
    ln_kernel<<<8192, 256, 0, stream>>>(x, g1, be1, h);
    // QKV projection
    gemm_bt<0><<<dim3(24, 64), 256, 0, stream>>>(h, wqkvT, qkv, nullptr, nullptr, 8192, 3072, 1024);
    // causal attention (balanced two-pass)
    attn_kernel<<<dim3(8, 64), 256, 0, stream>>>(qkv, o);
    // output proj + bias + residual -> x2 (f32)
    gemm_bt<1><<<dim3(8, 64), 256, 0, stream>>>(o, wpT, x2, bp, x, 8192, 1024, 1024);
    // LN2
    ln_kernel<<<8192, 256, 0, stream>>>(x2, g2, be2, h2);
    // FFN up + ReLU
    gemm_bt<2><<<dim3(32, 64), 256, 0, stream>>>(h2, w1T, act, b1, nullptr, 8192, 4096, 1024);
    // FFN down + bias + residual -> out (f32)
    gemm_bt<1><<<dim3(8, 64), 256, 0, stream>>>(act, w2T, d_out, b2, x2, 8192, 1024, 4096);
}

// Round 6
// 645.263 us; speedup vs baseline: 1.3972x; 1.0827x over previous
//
#include <hip/hip_runtime.h>
#include <hip/hip_bf16.h>
#include <cstdint>

typedef __bf16 bf16_t;
typedef bf16_t bf16x8 __attribute__((ext_vector_type(8)));
typedef float f32x4 __attribute__((ext_vector_type(4)));

#define DEVI __device__ __forceinline__

DEVI void gload_lds16(const void* g, void* l) {
    __builtin_amdgcn_global_load_lds((const __attribute__((address_space(1))) void*)g,
                                     (__attribute__((address_space(3))) void*)l, 16, 0, 0);
}

// ---------------- transpose + f32->bf16 pack: dst[n][k] = src[k][n] ----------------
__global__ __launch_bounds__(256) void transpose_f32_bf16(
    const float* __restrict__ src, bf16_t* __restrict__ dst,
    int ldsrc, int lddst, long srcBatchStride, long dstBatchStride)
{
    __shared__ float tile[32][33];
    src += (long)blockIdx.z * srcBatchStride;
    dst += (long)blockIdx.z * dstBatchStride;
    const int bx = blockIdx.x * 32;   // src col
    const int by = blockIdx.y * 32;   // src row
    const int tx = threadIdx.x, ty = threadIdx.y;
    #pragma unroll
    for (int j = 0; j < 32; j += 8)
        tile[ty + j][tx] = src[(size_t)(by + ty + j) * ldsrc + bx + tx];
    __syncthreads();
    #pragma unroll
    for (int j = 0; j < 32; j += 8)
        dst[(size_t)(bx + ty + j) * lddst + by + tx] = (bf16_t)tile[tx][ty + j];
}

// ---------------- LayerNorm (ddof=1 per reference), f32 in -> bf16 out ----------------
__global__ __launch_bounds__(256) void ln_kernel(
    const float* __restrict__ x, const float* __restrict__ g,
    const float* __restrict__ b, bf16_t* __restrict__ out)
{
    const int row = blockIdx.x;
    const int tid = threadIdx.x;
    __shared__ float red[8];
    const float4 v = ((const float4*)(x + (size_t)row * 1024))[tid];
    float s = v.x + v.y + v.z + v.w;
    #pragma unroll
    for (int m = 32; m; m >>= 1) s += __shfl_xor(s, m);
    if ((tid & 63) == 0) red[tid >> 6] = s;
    __syncthreads();
    const float mean = (red[0] + red[1] + red[2] + red[3]) * (1.f / 1024.f);
    const float dx = v.x - mean, dy = v.y - mean, dz = v.z - mean, dw = v.w - mean;
    float ss = dx * dx + dy * dy + dz * dz + dw * dw;
    #pragma unroll
    for (int m = 32; m; m >>= 1) ss += __shfl_xor(ss, m);
    if ((tid & 63) == 0) red[4 + (tid >> 6)] = ss;
    __syncthreads();
    const float var = (red[4] + red[5] + red[6] + red[7]) * (1.f / 1023.f);
    const float rstd = rsqrtf(var + 1e-5f);
    const float4 gv = ((const float4*)g)[tid];
    const float4 bv = ((const float4*)b)[tid];
    union { bf16_t h[4]; uint2 u; } pk;
    pk.h[0] = (bf16_t)(dx * rstd * gv.x + bv.x);
    pk.h[1] = (bf16_t)(dy * rstd * gv.y + bv.y);
    pk.h[2] = (bf16_t)(dz * rstd * gv.z + bv.z);
    pk.h[3] = (bf16_t)(dw * rstd * gv.w + bv.w);
    *((uint2*)(out + (size_t)row * 1024 + tid * 4)) = pk.u;
}

// ---------------- GEMM: C[M,N] = A[M,K] @ BT[N,K]^T, bf16 MFMA, f32 acc ----------------
// EPI 0: bf16 out (no bias).  EPI 1: f32 out = acc + bias + res.  EPI 2: bf16 out = relu(acc + bias).
template <int EPI>
__global__ __launch_bounds__(256) void gemm_bt(
    const bf16_t* __restrict__ A, const bf16_t* __restrict__ BT,
    void* __restrict__ Cout, const float* __restrict__ bias,
    const float* __restrict__ res, int M, int N, int K)
{
    constexpr int BK = 64;
    __shared__ bf16_t As[128 * BK];
    __shared__ bf16_t Bs[128 * BK];
    const int tid = threadIdx.x;
    const int lane = tid & 63;
    const int wid = tid >> 6;
    const int m0 = blockIdx.y * 128, n0 = blockIdx.x * 128;
    const int lrow = lane & 15, lgrp = lane >> 4;
    const int mw = (wid >> 1) * 64, nw = (wid & 1) * 64;
    f32x4 acc[4][4] = {};

    for (int k0 = 0; k0 < K; k0 += BK) {
        __syncthreads();
        #pragma unroll
        for (int i = 0; i < 4; ++i) {
            const int c = i * 256 + tid;
            const int row = c >> 3, kc = (c & 7) * 8;
            gload_lds16(A + (size_t)(m0 + row) * K + k0 + kc, &As[c * 8]);
        }
        #pragma unroll
        for (int i = 0; i < 4; ++i) {
            const int c = i * 256 + tid;
            const int row = c >> 3, kc = (c & 7) * 8;
            gload_lds16(BT + (size_t)(n0 + row) * K + k0 + kc, &Bs[c * 8]);
        }
        __syncthreads();
        #pragma unroll
        for (int kk = 0; kk < BK; kk += 32) {
            bf16x8 af[4], bfr[4];
            #pragma unroll
            for (int mi = 0; mi < 4; ++mi)
                af[mi] = *(const bf16x8*)&As[(mw + mi * 16 + lrow) * BK + kk + lgrp * 8];
            #pragma unroll
            for (int ni = 0; ni < 4; ++ni)
                bfr[ni] = *(const bf16x8*)&Bs[(nw + ni * 16 + lrow) * BK + kk + lgrp * 8];
            #pragma unroll
            for (int mi = 0; mi < 4; ++mi)
                #pragma unroll
                for (int ni = 0; ni < 4; ++ni)
                    acc[mi][ni] = __builtin_amdgcn_mfma_f32_16x16x32_bf16(
                        af[mi], bfr[ni], acc[mi][ni], 0, 0, 0);
        }
    }

    #pragma unroll
    for (int mi = 0; mi < 4; ++mi) {
        #pragma unroll
        for (int r = 0; r < 4; ++r) {
            const int row = m0 + mw + mi * 16 + lgrp * 4 + r;
            #pragma unroll
            for (int ni = 0; ni < 4; ++ni) {
                const int col = n0 + nw + ni * 16 + lrow;
                const float v = acc[mi][ni][r];
                if (EPI == 0) {
                    ((bf16_t*)Cout)[(size_t)row * N + col] = (bf16_t)v;
                } else if (EPI == 1) {
                    ((float*)Cout)[(size_t)row * N + col] =
                        v + bias[col] + res[(size_t)row * N + col];
                } else {
                    const float t = v + bias[col];
                    ((bf16_t*)Cout)[(size_t)row * N + col] = (bf16_t)(t > 0.f ? t : 0.f);
                }
            }
        }
    }
}

// ---------------- causal flash attention v4 ----------------
// Persistent blocks + atomic task queue (2048 tasks = 64 bh x 32 q-tiles, heavy-first).
// QBLK=64 (4 waves x 16 rows), KVBLK=64. Swapped QK^T (S^T in regs, q = lane&15):
// per-lane scalar m/l, 2-shfl row reduce, P redistributed to PV B-frags via shfl (no P LDS).
// Vt double-buffered + swizzled; ONE raw s_barrier (lgkm only) per tile. T13 defer-max.
__global__ __launch_bounds__(256, 3) void attn_kernel(
    const bf16_t* __restrict__ qkv, bf16_t* __restrict__ O, int* __restrict__ ctr)
{
    const int tid = threadIdx.x, lane = tid & 63, wid = tid >> 6;
    const int lrow = lane & 15, lgrp = lane >> 4;

    __shared__ bf16_t Vt[2][64 * 64];   // swizzled: (key,d) at d*64 + ((key>>3 ^ (d&7))<<3) + (key&7)
    __shared__ int s_task;

    // P-redistribution source lanes: target (lrow,g) reads lanes lrow+32*(g&1) and +16
    const int srcA = lrow + ((lgrp & 1) << 5);
    const int srcB = srcA + 16;
    const bool selHi = ((lgrp >> 1) & 1) != 0;

    // V staging: thread handles keys {vp, vp+1} x 8 d's
    const int vp  = (tid & 31) * 2;
    const int vdc = tid >> 5;

    for (;;) {
        __syncthreads();
        if (tid == 0) s_task = atomicAdd(ctr, 1);
        __syncthreads();
        const int task = s_task;
        if (task >= 2048) return;

        const int qt = 31 - (task >> 6);          // heavy q-tiles first
        const int bh = task & 63;
        const int b = bh >> 4, h = bh & 15;
        const bf16_t* base  = qkv + (size_t)b * 2048 * 3072;
        const bf16_t* Kbase = base + 1024 + h * 64;
        const bf16_t* Vbase = base + 2048 + h * 64;
        const int qb = qt * 64;
        const int nt = qt + 1;
        const int qrow = qb + wid * 16 + lrow;    // this lane's q-row

        // Q fragments (B-operand layout), pre-scaled by 8 (faithful * sqrt(hs))
        bf16x8 qf[2];
        #pragma unroll
        for (int dh = 0; dh < 2; ++dh) {
            bf16x8 t = *(const bf16x8*)(base + (size_t)qrow * 3072 + h * 64 + dh * 32 + lgrp * 8);
            #pragma unroll
            for (int j = 0; j < 8; ++j) t[j] = (bf16_t)((float)t[j] * 8.0f);
            qf[dh] = t;
        }

        f32x4 of[4] = {};
        float m = -1e30f, lp = 0.f;   // finite init: avoids inf-inf NaN on fully-masked lanes

        // prologue: prefetch tile 0 (V to regs, K frags)
        bf16x8 vvc0 = *(const bf16x8*)(Vbase + (size_t)(vp    ) * 3072 + vdc * 8);
        bf16x8 vvc1 = *(const bf16x8*)(Vbase + (size_t)(vp + 1) * 3072 + vdc * 8);
        bf16x8 kf[4][2];
        #pragma unroll
        for (int kt = 0; kt < 4; ++kt)
            #pragma unroll
            for (int dh = 0; dh < 2; ++dh)
                kf[kt][dh] = *(const bf16x8*)(Kbase + (size_t)(kt * 16 + lrow) * 3072 + dh * 32 + lgrp * 8);

        int cb = 0;
        for (int t = 0; t < nt; ++t) {
            // ---- (a) write V tile t (transposed+swizzled), b32 pairs ----
            bf16_t* vt = Vt[cb];
            #pragma unroll
            for (int j = 0; j < 8; ++j) {
                const int d = vdc * 8 + j;
                union { bf16_t h2[2]; uint32_t u; } w2;
                w2.h2[0] = vvc0[j]; w2.h2[1] = vvc1[j];
                *(uint32_t*)&vt[d * 64 + (((vp >> 3) ^ (d & 7)) << 3) + (vp & 7)] = w2.u;
            }

            // ---- (b) prefetch tile t+1 (flies across the barrier) ----
            const bool hasn = (t + 1 < nt);
            bf16x8 vvn0, vvn1, kfn[4][2];
            if (hasn) {
                const int kv2 = (t + 1) << 6;
                vvn0 = *(const bf16x8*)(Vbase + (size_t)(kv2 + vp    ) * 3072 + vdc * 8);
                vvn1 = *(const bf16x8*)(Vbase + (size_t)(kv2 + vp + 1) * 3072 + vdc * 8);
                #pragma unroll
                for (int kt = 0; kt < 4; ++kt)
                    #pragma unroll
                    for (int dh = 0; dh < 2; ++dh)
                        kfn[kt][dh] = *(const bf16x8*)(Kbase + (size_t)(kv2 + kt * 16 + lrow) * 3072
                                                       + dh * 32 + lgrp * 8);
            }

            // ---- (c) swapped QK^T: sT[kt][r] = S^T[key=kt*16+lgrp*4+r][q=lrow] ----
            f32x4 sT[4] = {};
            __builtin_amdgcn_s_setprio(1);
            #pragma unroll
            for (int kt = 0; kt < 4; ++kt) {
                sT[kt] = __builtin_amdgcn_mfma_f32_16x16x32_bf16(kf[kt][0], qf[0], sT[kt], 0, 0, 0);
                sT[kt] = __builtin_amdgcn_mfma_f32_16x16x32_bf16(kf[kt][1], qf[1], sT[kt], 0, 0, 0);
            }
            __builtin_amdgcn_s_setprio(0);

            // ---- (d) causal mask: diagonal tile only ----
            if (t == nt - 1) {
                #pragma unroll
                for (int kt = 0; kt < 4; ++kt)
                    #pragma unroll
                    for (int r = 0; r < 4; ++r)
                        if (kt * 16 + lgrp * 4 + r > wid * 16 + lrow) sT[kt][r] = -INFINITY;
            }

            // ---- (e) online softmax, per-lane scalar state ----
            float pmax = -INFINITY;
            #pragma unroll
            for (int kt = 0; kt < 4; ++kt)
                pmax = fmaxf(pmax, fmaxf(fmaxf(sT[kt][0], sT[kt][1]), fmaxf(sT[kt][2], sT[kt][3])));
            pmax = fmaxf(pmax, __shfl_xor(pmax, 16));
            pmax = fmaxf(pmax, __shfl_xor(pmax, 32));
            if (__any(pmax > m + 8.f)) {           // T13 defer-max, wave-uniform
                const float mnew = fmaxf(m, pmax);
                const float alpha = __expf(m - mnew);
                m = mnew;
                lp *= alpha;
                #pragma unroll
                for (int dg = 0; dg < 4; ++dg) of[dg] *= alpha;
            }
            uint32_t pk[4][2];
            float sum = 0.f;
            #pragma unroll
            for (int kt = 0; kt < 4; ++kt) {
                const float p0 = __expf(sT[kt][0] - m), p1 = __expf(sT[kt][1] - m);
                const float p2 = __expf(sT[kt][2] - m), p3 = __expf(sT[kt][3] - m);
                sum += (p0 + p1) + (p2 + p3);
                union { bf16_t h2[2]; uint32_t u; } w0, w1;
                w0.h2[0] = (bf16_t)p0; w0.h2[1] = (bf16_t)p1;
                w1.h2[0] = (bf16_t)p2; w1.h2[1] = (bf16_t)p3;
                pk[kt][0] = w0.u; pk[kt][1] = w1.u;
            }
            lp += sum;

            // ---- (f) redistribute P^T into PV B-fragments via shfl ----
            uint32_t W[2][4];
            #pragma unroll
            for (int kh = 0; kh < 2; ++kh) {
                const int k0 = kh * 2, k1 = kh * 2 + 1;
                const uint32_t a0 = __shfl(pk[k0][0], srcA), b0 = __shfl(pk[k1][0], srcA);
                const uint32_t a1 = __shfl(pk[k0][1], srcA), b1 = __shfl(pk[k1][1], srcA);
                const uint32_t a2 = __shfl(pk[k0][0], srcB), b2 = __shfl(pk[k1][0], srcB);
                const uint32_t a3 = __shfl(pk[k0][1], srcB), b3 = __shfl(pk[k1][1], srcB);
                W[kh][0] = selHi ? b0 : a0;
                W[kh][1] = selHi ? b1 : a1;
                W[kh][2] = selHi ? b2 : a2;
                W[kh][3] = selHi ? b3 : a3;
            }

            // ---- (g) single barrier per tile: Vt[cb] visible, lgkm only ----
            asm volatile("s_waitcnt lgkmcnt(0)\n\ts_barrier" ::: "memory");

            // ---- (h) PV: of += V^T x P^T ----
            __builtin_amdgcn_s_setprio(1);
            #pragma unroll
            for (int kh = 0; kh < 2; ++kh) {
                union { uint32_t u[4]; bf16x8 v; } pb;
                pb.u[0] = W[kh][0]; pb.u[1] = W[kh][1]; pb.u[2] = W[kh][2]; pb.u[3] = W[kh][3];
                #pragma unroll
                for (int dg = 0; dg < 4; ++dg) {
                    const int d = dg * 16 + lrow;
                    const bf16x8 vf = *(const bf16x8*)&vt[d * 64 + (((kh * 4 + lgrp) ^ (d & 7)) << 3)];
                    of[dg] = __builtin_amdgcn_mfma_f32_16x16x32_bf16(vf, pb.v, of[dg], 0, 0, 0);
                }
            }
            __builtin_amdgcn_s_setprio(0);

            // ---- (i) rotate prefetch ----
            if (hasn) {
                vvc0 = vvn0; vvc1 = vvn1;
                #pragma unroll
                for (int kt = 0; kt < 4; ++kt) {
                    kf[kt][0] = kfn[kt][0];
                    kf[kt][1] = kfn[kt][1];
                }
            }
            cb ^= 1;
        }

        // ---- epilogue: reduce lane-partial l over lgrp, write O^T-regs as O ----
        lp += __shfl_xor(lp, 16);
        lp += __shfl_xor(lp, 32);
        const float rl = 1.f / lp;
        bf16_t* orow = O + (size_t)(b * 2048 + qrow) * 1024 + h * 64;
        #pragma unroll
        for (int dg = 0; dg < 4; ++dg) {
            union { bf16_t h4[4]; uint2 u; } w;
            #pragma unroll
            for (int r = 0; r < 4; ++r) w.h4[r] = (bf16_t)(of[dg][r] * rl);
            *(uint2*)&orow[dg * 16 + lgrp * 4] = w.u;
        }
    }
}

// ---------------- host ----------------
extern "C" void kernel_launch(void* const* d_in, const int* in_sizes, int n_in,
                              void* d_out, int out_size, void* d_ws, size_t ws_size,
                              hipStream_t stream)
{
    const float* x   = (const float*)d_in[0];
    const float* Wq  = (const float*)d_in[1];
    const float* Wk  = (const float*)d_in[2];
    const float* Wv  = (const float*)d_in[3];
    const float* Wp  = (const float*)d_in[4];
    const float* bp  = (const float*)d_in[5];
    const float* W1  = (const float*)d_in[6];
    const float* b1  = (const float*)d_in[7];
    const float* W2  = (const float*)d_in[8];
    const float* b2  = (const float*)d_in[9];
    const float* g1  = (const float*)d_in[10];
    const float* be1 = (const float*)d_in[11];
    const float* g2  = (const float*)d_in[12];
    const float* be2 = (const float*)d_in[13];

    char* w = (char*)d_ws;
    auto alloc = [&](size_t bytes) { char* p = w; w += (bytes + 255) & ~255ull; return p; };
    bf16_t* wqkvT = (bf16_t*)alloc((size_t)3072 * 1024 * 2);
    bf16_t* wpT   = (bf16_t*)alloc((size_t)1024 * 1024 * 2);
    bf16_t* w1T   = (bf16_t*)alloc((size_t)4096 * 1024 * 2);
    bf16_t* w2T   = (bf16_t*)alloc((size_t)1024 * 4096 * 2);
    bf16_t* h     = (bf16_t*)alloc((size_t)8192 * 1024 * 2);
    bf16_t* qkv   = (bf16_t*)alloc((size_t)8192 * 3072 * 2);
    float*  x2    = (float*)alloc((size_t)8192 * 1024 * 4);
    bf16_t* act   = (bf16_t*)alloc((size_t)8192 * 4096 * 2);
    int*    ctr   = (int*)alloc(256);
    bf16_t* o     = h;    // h dead after QKV GEMM
    bf16_t* h2    = qkv;  // qkv dead after attention

    hipMemsetAsync(ctr, 0, 4, stream);   // task counter for persistent attention kernel

    const dim3 tblk(32, 8);
    // pack weights (transposed, bf16)
    transpose_f32_bf16<<<dim3(2, 32, 16), tblk, 0, stream>>>(Wq, wqkvT,                64, 1024, 1024 * 64, 64 * 1024);
    transpose_f32_bf16<<<dim3(2, 32, 16), tblk, 0, stream>>>(Wk, wqkvT + 1024 * 1024,  64, 1024, 1024 * 64, 64 * 1024);
    transpose_f32_bf16<<<dim3(2, 32, 16), tblk, 0, stream>>>(Wv, wqkvT + 2048 * 1024,  64, 1024, 1024 * 64, 64 * 1024);
    transpose_f32_bf16<<<dim3(32, 32, 1),  tblk, 0, stream>>>(Wp, wpT, 1024, 1024, 0, 0);
    transpose_f32_bf16<<<dim3(128, 32, 1), tblk, 0, stream>>>(W1, w1T, 4096, 1024, 0, 0);
    transpose_f32_bf16<<<dim3(32, 128, 1), tblk, 0, stream>>>(W2, w2T, 1024, 4096, 0, 0);

    // LN1
    ln_kernel<<<8192, 256, 0, stream>>>(x, g1, be1, h);
    // QKV projection
    gemm_bt<0><<<dim3(24, 64), 256, 0, stream>>>(h, wqkvT, qkv, nullptr, nullptr, 8192, 3072, 1024);
    // causal attention (persistent, dynamic tasks)
    attn_kernel<<<768, 256, 0, stream>>>(qkv, o, ctr);
    // output proj + bias + residual -> x2 (f32)
    gemm_bt<1><<<dim3(8, 64), 256, 0, stream>>>(o, wpT, x2, bp, x, 8192, 1024, 1024);
    // LN2
    ln_kernel<<<8192, 256, 0, stream>>>(x2, g2, be2, h2);
    // FFN up + ReLU
    gemm_bt<2><<<dim3(32, 64), 256, 0, stream>>>(h2, w1T, act, b1, nullptr, 8192, 4096, 1024);
    // FFN down + bias + residual -> out (f32)
    gemm_bt<1><<<dim3(8, 64), 256, 0, stream>>>(act, w2T, d_out, b2, x2, 8192, 1024, 4096);
}